// Round 1
// baseline (304.196 us; speedup 1.0000x reference)
//
#include <hip/hip_runtime.h>
#include <stdint.h>

// DynamicSparseLinearAttention on MI355X.
// N=4, L=8192, H=8, D=V=128. Layout [n][l][h][d], row stride H*D = 1024 floats.
//
// Phase 1 (kv_reduce): KVT[nh][v][d] = sum_s featmap(K[s,d]) * values[s,v]  (UNSCALED:
//   the /L on values and *L on out cancel), Ksum[nh][d] = sum_s featmap(K[s,d]).
//   fp32 vector outer-product, split-L over 8 chunks, fp32 atomics into d_ws.
// Phase 2 (attn_out): out[l,v] = (Qf[l,:] @ KV) * Z[l],
//   Z = 1/(where(score>thr, score, 0)+eps), score = Qf . Ksum (fp32).
//   bf16 MFMA 16x16x32, LDS XOR-swizzled tiles (error budget: bf16 inputs give
//   ~2e-6 abs error on out, threshold is 8.4e-4).

#define LSEQ 8192
#define NHD  1024   // H*D
#define DD   128

typedef __attribute__((ext_vector_type(4))) float f32x4;
typedef __attribute__((ext_vector_type(8))) short bf16x8;

static __device__ __forceinline__ unsigned short f2bf(float x) {
  union { float f; uint32_t u; } v; v.f = x;
  uint32_t r = v.u + 0x7FFFu + ((v.u >> 16) & 1u);  // RNE
  return (unsigned short)(r >> 16);
}
static __device__ __forceinline__ float featmap(float x) {
  // elu(x)+1 = x+1 (x>0) else exp(x)
  return x > 0.f ? x + 1.f : __expf(x);
}

// ---------------- Phase 1 ----------------
__global__ __launch_bounds__(512) void kv_reduce(const float* __restrict__ keys,
                                                 const float* __restrict__ values,
                                                 float* __restrict__ kvt,
                                                 float* __restrict__ ksumg) {
  const int tid = threadIdx.x;
  const int chunk = blockIdx.x;   // 0..7, each covers 1024 s-rows
  const int nh = blockIdx.y;      // 0..31
  const int n = nh >> 3, h = nh & 7;
  const size_t base = (size_t)n * LSEQ * NHD + (size_t)h * DD;

  __shared__ float kls[16][128];
  __shared__ float vls[16][128];
  __shared__ float ks2[16][128];

  const int r  = tid >> 5;   // 0..15 : tile row (stage) == d-group (compute)
  const int c4 = tid & 31;   // 0..31 : float4 col (stage) == v-group (compute)
  const int d0 = r * 8;
  const int v0 = c4 * 4;

  float acc[8][4];
#pragma unroll
  for (int j = 0; j < 8; ++j)
#pragma unroll
    for (int i = 0; i < 4; ++i) acc[j][i] = 0.f;
  float ksp[4] = {0.f, 0.f, 0.f, 0.f};

  const float* kp = keys + base + (size_t)r * NHD + v0;
  const float* vp = values + base + (size_t)r * NHD + v0;
  const int sbeg = chunk * 1024;

  float4 kq = *(const float4*)(kp + (size_t)sbeg * NHD);
  float4 vq = *(const float4*)(vp + (size_t)sbeg * NHD);

  for (int s0 = 0; s0 < 1024; s0 += 16) {
    float4 kf;
    kf.x = featmap(kq.x); kf.y = featmap(kq.y);
    kf.z = featmap(kq.z); kf.w = featmap(kq.w);
    ksp[0] += kf.x; ksp[1] += kf.y; ksp[2] += kf.z; ksp[3] += kf.w;
    *(float4*)&kls[r][v0] = kf;
    *(float4*)&vls[r][v0] = vq;
    __syncthreads();
    if (s0 + 16 < 1024) {   // prefetch next tile while computing this one
      kq = *(const float4*)(kp + (size_t)(sbeg + s0 + 16) * NHD);
      vq = *(const float4*)(vp + (size_t)(sbeg + s0 + 16) * NHD);
    }
#pragma unroll
    for (int s = 0; s < 16; ++s) {
      f32x4 ka = *(const f32x4*)&kls[s][d0];
      f32x4 kb = *(const f32x4*)&kls[s][d0 + 4];
      f32x4 vv = *(const f32x4*)&vls[s][v0];
#pragma unroll
      for (int j = 0; j < 4; ++j)
#pragma unroll
        for (int i = 0; i < 4; ++i) {
          acc[j][i]     += ka[j] * vv[i];
          acc[j + 4][i] += kb[j] * vv[i];
        }
    }
    __syncthreads();
  }

  // Ksum: per-thread partials -> LDS -> 128 threads reduce -> global atomic
  ks2[r][v0 + 0] = ksp[0]; ks2[r][v0 + 1] = ksp[1];
  ks2[r][v0 + 2] = ksp[2]; ks2[r][v0 + 3] = ksp[3];
  __syncthreads();
  if (tid < 128) {
    float s = 0.f;
#pragma unroll
    for (int rr = 0; rr < 16; ++rr) s += ks2[rr][tid];
    atomicAdd(&ksumg[nh * 128 + tid], s);
  }

  // KV partial: atomic into KVT[nh][v][d]
  float* dst = kvt + (size_t)nh * 16384;
#pragma unroll
  for (int i = 0; i < 4; ++i)
#pragma unroll
    for (int j = 0; j < 8; ++j)
      atomicAdd(&dst[(v0 + i) * 128 + d0 + j], acc[j][i]);
}

// ---------------- Phase 2 ----------------
// LDS tiles stored bf16 as uint32 pairs; 16B chunk index swizzle: ch = r*16 + (c8 ^ (r&7)).
__global__ __launch_bounds__(256) void attn_out(const float* __restrict__ queries,
                                                const float* __restrict__ kvt,
                                                const float* __restrict__ ksumg,
                                                const float* __restrict__ thrp,
                                                float* __restrict__ out) {
  const int tid = threadIdx.x;
  const int mc = blockIdx.x;   // 0..63 : 128-row tile
  const int nh = blockIdx.y;   // 0..31
  const int n = nh >> 3, h = nh & 7;
  const int l0 = mc * 128;
  const size_t qoff = ((size_t)n * LSEQ + l0) * NHD + (size_t)h * DD;

  __shared__ __align__(16) uint32_t As[128 * 64];  // Qf bf16 [128 rows][128 d]
  __shared__ __align__(16) uint32_t Bs[128 * 64];  // KVT bf16 [128 v][128 d]
  __shared__ float ksum_s[128];
  __shared__ float spart[128];
  __shared__ float zrow[128];

  if (tid < 128) ksum_s[tid] = ksumg[nh * 128 + tid];

  const float* kvp = kvt + (size_t)nh * 16384;
#pragma unroll
  for (int it = 0; it < 16; ++it) {
    int fi = it * 256 + tid;
    int rr = fi >> 5, c4 = fi & 31;
    float4 q = *(const float4*)(queries + qoff + (size_t)rr * NHD + c4 * 4);
    uint32_t p01 = (uint32_t)f2bf(featmap(q.x)) | ((uint32_t)f2bf(featmap(q.y)) << 16);
    uint32_t p23 = (uint32_t)f2bf(featmap(q.z)) | ((uint32_t)f2bf(featmap(q.w)) << 16);
    int ch = rr * 16 + ((c4 >> 1) ^ (rr & 7));
    As[ch * 4 + (c4 & 1) * 2]     = p01;
    As[ch * 4 + (c4 & 1) * 2 + 1] = p23;
  }
#pragma unroll
  for (int it = 0; it < 16; ++it) {
    int fi = it * 256 + tid;
    int rr = fi >> 5, c4 = fi & 31;
    float4 q = *(const float4*)(kvp + fi * 4);
    uint32_t p01 = (uint32_t)f2bf(q.x) | ((uint32_t)f2bf(q.y) << 16);
    uint32_t p23 = (uint32_t)f2bf(q.z) | ((uint32_t)f2bf(q.w) << 16);
    int ch = rr * 16 + ((c4 >> 1) ^ (rr & 7));
    Bs[ch * 4 + (c4 & 1) * 2]     = p01;
    Bs[ch * 4 + (c4 & 1) * 2 + 1] = p23;
  }
  __syncthreads();

  // scores: 2 threads per row, fp32 dot(Qf_bf16, Ksum)
  {
    int rr = tid & 127, half = tid >> 7;
    float sum = 0.f;
#pragma unroll
    for (int cc = 0; cc < 8; ++cc) {
      int c8 = half * 8 + cc;
      uint4 raw = *(const uint4*)&As[(rr * 16 + (c8 ^ (rr & 7))) * 4];
      const float* kk = &ksum_s[c8 * 8];
      sum += __uint_as_float(raw.x << 16) * kk[0];
      sum += __uint_as_float(raw.x & 0xFFFF0000u) * kk[1];
      sum += __uint_as_float(raw.y << 16) * kk[2];
      sum += __uint_as_float(raw.y & 0xFFFF0000u) * kk[3];
      sum += __uint_as_float(raw.z << 16) * kk[4];
      sum += __uint_as_float(raw.z & 0xFFFF0000u) * kk[5];
      sum += __uint_as_float(raw.w << 16) * kk[6];
      sum += __uint_as_float(raw.w & 0xFFFF0000u) * kk[7];
    }
    if (half) spart[rr] = sum;
    __syncthreads();
    if (!half) {
      float score = sum + spart[rr];
      float thr = thrp[0];
      float sp = score > thr ? score : 0.f;
      zrow[rr] = 1.f / (sp + 1e-6f);
    }
    __syncthreads();
  }

  // MFMA: wave w owns rows [w*32, w*32+32), all 128 cols.
  const int lane = tid & 63;
  const int w = tid >> 6;
  const int lr = lane & 15, lg = lane >> 4;
  f32x4 acc0[8] = {};
  f32x4 acc1[8] = {};
#pragma unroll
  for (int ks = 0; ks < 4; ++ks) {
    int c8 = ks * 4 + lg;                 // 16B chunk of the lane's 8 k-values
    int cs = c8 ^ (lr & 7);               // swizzled (row&7 == lr&7 for all rows used)
    int r0 = w * 32 + lr;
    bf16x8 a0 = *(const bf16x8*)&As[(r0 * 16 + cs) * 4];
    bf16x8 a1 = *(const bf16x8*)&As[((r0 + 16) * 16 + cs) * 4];
#pragma unroll
    for (int ct = 0; ct < 8; ++ct) {
      int v = ct * 16 + lr;
      bf16x8 b = *(const bf16x8*)&Bs[(v * 16 + cs) * 4];
      acc0[ct] = __builtin_amdgcn_mfma_f32_16x16x32_bf16(a0, b, acc0[ct], 0, 0, 0);
      acc1[ct] = __builtin_amdgcn_mfma_f32_16x16x32_bf16(a1, b, acc1[ct], 0, 0, 0);
    }
  }

  float z0[4], z1[4];
#pragma unroll
  for (int j = 0; j < 4; ++j) {
    z0[j] = zrow[w * 32 + lg * 4 + j];
    z1[j] = zrow[w * 32 + 16 + lg * 4 + j];
  }
  float* op = out + qoff;
#pragma unroll
  for (int ct = 0; ct < 8; ++ct)
#pragma unroll
    for (int j = 0; j < 4; ++j) {
      int row = w * 32 + lg * 4 + j;   // C/D layout: col=lane&15, row=(lane>>4)*4+j
      op[(size_t)row * NHD + ct * 16 + lr]        = acc0[ct][j] * z0[j];
      op[(size_t)(row + 16) * NHD + ct * 16 + lr] = acc1[ct][j] * z1[j];
    }
}

extern "C" void kernel_launch(void* const* d_in, const int* in_sizes, int n_in,
                              void* d_out, int out_size, void* d_ws, size_t ws_size,
                              hipStream_t stream) {
  const float* queries  = (const float*)d_in[0];
  const float* keys     = (const float*)d_in[1];
  const float* values   = (const float*)d_in[2];
  const float* threshold = (const float*)d_in[3];
  float* out = (float*)d_out;

  float* kvt   = (float*)d_ws;           // 32*128*128 fp32 = 2 MiB
  float* ksumg = kvt + 32 * 16384;       // 32*128 fp32

  hipMemsetAsync(d_ws, 0, (size_t)(32 * 16384 + 32 * 128) * sizeof(float), stream);
  kv_reduce<<<dim3(8, 32), 512, 0, stream>>>(keys, values, kvt, ksumg);
  attn_out<<<dim3(64, 32), 256, 0, stream>>>(queries, kvt, ksumg, threshold, out);
}

// Round 2
// 264.712 us; speedup vs baseline: 1.1492x; 1.1492x over previous
//
#include <hip/hip_runtime.h>
#include <stdint.h>

// DynamicSparseLinearAttention on MI355X.
// N=4, L=8192, H=8, D=V=128. Layout [n][l][h][d], row stride H*D = 1024 floats.
//
// Phase 1 (kv_reduce_mfma): KVT[nh][v][d] = sum_s featmap(K[s,d]) * values[s,v]
//   (UNSCALED: the /L on values and *L on out cancel), Ksum[nh][d] = sum_s featmap(K).
//   bf16 MFMA 16x16x32, fragments built directly from global (per-element b32 loads
//   = 4x64B coalesced segments per instr; no LDS, no barriers). Split-s over 16
//   chunks, fp32 atomics into d_ws. bf16 rounding here contributes ~2e-6 absmax
//   (incoherent noise / score~1.4e6), negligible vs the 8.4e-4 threshold.
// Phase 2 (attn_out): out[l,v] = (Qf[l,:] @ KV) * Z[l],
//   Z = 1/(where(score>thr, score, 0)+eps), score = Qf . Ksum (fp32).
//   bf16 MFMA 16x16x32, LDS XOR-swizzled tiles.

#define LSEQ 8192
#define NHD  1024   // H*D
#define DD   128

typedef __attribute__((ext_vector_type(4))) float f32x4;
typedef __attribute__((ext_vector_type(8))) short bf16x8;

static __device__ __forceinline__ unsigned short f2bf(float x) {
  union { float f; uint32_t u; } v; v.f = x;
  uint32_t r = v.u + 0x7FFFu + ((v.u >> 16) & 1u);  // RNE
  return (unsigned short)(r >> 16);
}
static __device__ __forceinline__ float featmap(float x) {
  // elu(x)+1 = x+1 (x>0) else exp(x)
  return x > 0.f ? x + 1.f : __expf(x);
}

// ---------------- Phase 1: MFMA reduction ----------------
// Grid (16 chunks, 32 nh), 512 threads = 8 waves = 2 (d) x 4 (v).
// Wave covers d in [wr*64, +64) x v in [wc*32, +32); K-step 32 (one MFMA).
__global__ __launch_bounds__(512) void kv_reduce_mfma(const float* __restrict__ keys,
                                                      const float* __restrict__ values,
                                                      float* __restrict__ kvt,
                                                      float* __restrict__ ksumg) {
  const int tid = threadIdx.x;
  const int chunk = blockIdx.x;   // 0..15, each covers 512 s-rows
  const int nh = blockIdx.y;      // 0..31
  const int n = nh >> 3, h = nh & 7;
  const size_t base = (size_t)n * LSEQ * NHD + (size_t)h * DD;

  const int lane = tid & 63;
  const int w = tid >> 6;
  const int wr = w >> 2, wc = w & 3;     // wave row (d), wave col (v)
  const int lr = lane & 15, lg = lane >> 4;

  f32x4 acc[4][2] = {};
  float ksp[4] = {0.f, 0.f, 0.f, 0.f};

  // lane-private base: s-row = chunk*512 + lg*8 (+j), col = block offset + lr
  const float* kbase = keys   + base + (size_t)(chunk * 512 + lg * 8) * NHD + wr * 64 + lr;
  const float* vbase = values + base + (size_t)(chunk * 512 + lg * 8) * NHD + wc * 32 + lr;

  for (int s0 = 0; s0 < 512; s0 += 32) {
    bf16x8 af[4];
#pragma unroll
    for (int fr = 0; fr < 4; ++fr) {
      const float* kp = kbase + (size_t)s0 * NHD + fr * 16;
      float f[8];
#pragma unroll
      for (int j = 0; j < 8; ++j) f[j] = featmap(kp[(size_t)j * NHD]);
      if (wc == 0) {   // wave-column 0 owns Ksum (each K element touched once there)
#pragma unroll
        for (int j = 0; j < 8; ++j) ksp[fr] += f[j];
      }
#pragma unroll
      for (int j = 0; j < 8; ++j) af[fr][j] = (short)f2bf(f[j]);
    }
    bf16x8 bfr[2];
#pragma unroll
    for (int fc = 0; fc < 2; ++fc) {
      const float* vp = vbase + (size_t)s0 * NHD + fc * 16;
#pragma unroll
      for (int j = 0; j < 8; ++j) bfr[fc][j] = (short)f2bf(vp[(size_t)j * NHD]);
    }
#pragma unroll
    for (int fr = 0; fr < 4; ++fr)
#pragma unroll
      for (int fc = 0; fc < 2; ++fc)
        acc[fr][fc] = __builtin_amdgcn_mfma_f32_16x16x32_bf16(af[fr], bfr[fc], acc[fr][fc], 0, 0, 0);
  }

  // Ksum: reduce lane partials across the 4 k-groups, then atomic per d.
  if (wc == 0) {
#pragma unroll
    for (int fr = 0; fr < 4; ++fr) {
      float v = ksp[fr];
      v += __shfl_xor(v, 16, 64);
      v += __shfl_xor(v, 32, 64);
      if (lane < 16)
        atomicAdd(&ksumg[nh * 128 + wr * 64 + fr * 16 + lane], v);
    }
  }

  // KV partials: C/D layout col(v)=lane&15, row(d)=(lane>>4)*4+j. Store KVT[v][d].
  float* dst = kvt + (size_t)nh * 16384;
#pragma unroll
  for (int fr = 0; fr < 4; ++fr)
#pragma unroll
    for (int fc = 0; fc < 2; ++fc)
#pragma unroll
      for (int j = 0; j < 4; ++j) {
        int d = wr * 64 + fr * 16 + lg * 4 + j;
        int v = wc * 32 + fc * 16 + lr;
        atomicAdd(&dst[v * 128 + d], acc[fr][fc][j]);
      }
}

// ---------------- Phase 2 ----------------
// LDS tiles stored bf16 as uint32 pairs; 16B chunk index swizzle: ch = r*16 + (c8 ^ (r&7)).
__global__ __launch_bounds__(256) void attn_out(const float* __restrict__ queries,
                                                const float* __restrict__ kvt,
                                                const float* __restrict__ ksumg,
                                                const float* __restrict__ thrp,
                                                float* __restrict__ out) {
  const int tid = threadIdx.x;
  const int mc = blockIdx.x;   // 0..63 : 128-row tile
  const int nh = blockIdx.y;   // 0..31
  const int n = nh >> 3, h = nh & 7;
  const int l0 = mc * 128;
  const size_t qoff = ((size_t)n * LSEQ + l0) * NHD + (size_t)h * DD;

  __shared__ __align__(16) uint32_t As[128 * 64];  // Qf bf16 [128 rows][128 d]
  __shared__ __align__(16) uint32_t Bs[128 * 64];  // KVT bf16 [128 v][128 d]
  __shared__ float ksum_s[128];
  __shared__ float spart[128];
  __shared__ float zrow[128];

  if (tid < 128) ksum_s[tid] = ksumg[nh * 128 + tid];

  const float* kvp = kvt + (size_t)nh * 16384;
#pragma unroll
  for (int it = 0; it < 16; ++it) {
    int fi = it * 256 + tid;
    int rr = fi >> 5, c4 = fi & 31;
    float4 q = *(const float4*)(queries + qoff + (size_t)rr * NHD + c4 * 4);
    uint32_t p01 = (uint32_t)f2bf(featmap(q.x)) | ((uint32_t)f2bf(featmap(q.y)) << 16);
    uint32_t p23 = (uint32_t)f2bf(featmap(q.z)) | ((uint32_t)f2bf(featmap(q.w)) << 16);
    int ch = rr * 16 + ((c4 >> 1) ^ (rr & 7));
    As[ch * 4 + (c4 & 1) * 2]     = p01;
    As[ch * 4 + (c4 & 1) * 2 + 1] = p23;
  }
#pragma unroll
  for (int it = 0; it < 16; ++it) {
    int fi = it * 256 + tid;
    int rr = fi >> 5, c4 = fi & 31;
    float4 q = *(const float4*)(kvp + fi * 4);
    uint32_t p01 = (uint32_t)f2bf(q.x) | ((uint32_t)f2bf(q.y) << 16);
    uint32_t p23 = (uint32_t)f2bf(q.z) | ((uint32_t)f2bf(q.w) << 16);
    int ch = rr * 16 + ((c4 >> 1) ^ (rr & 7));
    Bs[ch * 4 + (c4 & 1) * 2]     = p01;
    Bs[ch * 4 + (c4 & 1) * 2 + 1] = p23;
  }
  __syncthreads();

  // scores: 2 threads per row, fp32 dot(Qf_bf16, Ksum)
  {
    int rr = tid & 127, half = tid >> 7;
    float sum = 0.f;
#pragma unroll
    for (int cc = 0; cc < 8; ++cc) {
      int c8 = half * 8 + cc;
      uint4 raw = *(const uint4*)&As[(rr * 16 + (c8 ^ (rr & 7))) * 4];
      const float* kk = &ksum_s[c8 * 8];
      sum += __uint_as_float(raw.x << 16) * kk[0];
      sum += __uint_as_float(raw.x & 0xFFFF0000u) * kk[1];
      sum += __uint_as_float(raw.y << 16) * kk[2];
      sum += __uint_as_float(raw.y & 0xFFFF0000u) * kk[3];
      sum += __uint_as_float(raw.z << 16) * kk[4];
      sum += __uint_as_float(raw.z & 0xFFFF0000u) * kk[5];
      sum += __uint_as_float(raw.w << 16) * kk[6];
      sum += __uint_as_float(raw.w & 0xFFFF0000u) * kk[7];
    }
    if (half) spart[rr] = sum;
    __syncthreads();
    if (!half) {
      float score = sum + spart[rr];
      float thr = thrp[0];
      float sp = score > thr ? score : 0.f;
      zrow[rr] = 1.f / (sp + 1e-6f);
    }
    __syncthreads();
  }

  // MFMA: wave w owns rows [w*32, w*32+32), all 128 cols.
  const int lane = tid & 63;
  const int w = tid >> 6;
  const int lr = lane & 15, lg = lane >> 4;
  f32x4 acc0[8] = {};
  f32x4 acc1[8] = {};
#pragma unroll
  for (int ks = 0; ks < 4; ++ks) {
    int c8 = ks * 4 + lg;                 // 16B chunk of the lane's 8 k-values
    int cs = c8 ^ (lr & 7);               // swizzled (row&7 == lr&7 for all rows used)
    int r0 = w * 32 + lr;
    bf16x8 a0 = *(const bf16x8*)&As[(r0 * 16 + cs) * 4];
    bf16x8 a1 = *(const bf16x8*)&As[((r0 + 16) * 16 + cs) * 4];
#pragma unroll
    for (int ct = 0; ct < 8; ++ct) {
      int v = ct * 16 + lr;
      bf16x8 b = *(const bf16x8*)&Bs[(v * 16 + cs) * 4];
      acc0[ct] = __builtin_amdgcn_mfma_f32_16x16x32_bf16(a0, b, acc0[ct], 0, 0, 0);
      acc1[ct] = __builtin_amdgcn_mfma_f32_16x16x32_bf16(a1, b, acc1[ct], 0, 0, 0);
    }
  }

  float z0[4], z1[4];
#pragma unroll
  for (int j = 0; j < 4; ++j) {
    z0[j] = zrow[w * 32 + lg * 4 + j];
    z1[j] = zrow[w * 32 + 16 + lg * 4 + j];
  }
  float* op = out + qoff;
#pragma unroll
  for (int ct = 0; ct < 8; ++ct)
#pragma unroll
    for (int j = 0; j < 4; ++j) {
      int row = w * 32 + lg * 4 + j;   // C/D layout: col=lane&15, row=(lane>>4)*4+j
      op[(size_t)row * NHD + ct * 16 + lr]        = acc0[ct][j] * z0[j];
      op[(size_t)(row + 16) * NHD + ct * 16 + lr] = acc1[ct][j] * z1[j];
    }
}

extern "C" void kernel_launch(void* const* d_in, const int* in_sizes, int n_in,
                              void* d_out, int out_size, void* d_ws, size_t ws_size,
                              hipStream_t stream) {
  const float* queries  = (const float*)d_in[0];
  const float* keys     = (const float*)d_in[1];
  const float* values   = (const float*)d_in[2];
  const float* threshold = (const float*)d_in[3];
  float* out = (float*)d_out;

  float* kvt   = (float*)d_ws;           // 32*128*128 fp32 = 2 MiB
  float* ksumg = kvt + 32 * 16384;       // 32*128 fp32

  hipMemsetAsync(d_ws, 0, (size_t)(32 * 16384 + 32 * 128) * sizeof(float), stream);
  kv_reduce_mfma<<<dim3(16, 32), 512, 0, stream>>>(keys, values, kvt, ksumg);
  attn_out<<<dim3(64, 32), 256, 0, stream>>>(queries, kvt, ksumg, threshold, out);
}